// Round 5
// baseline (3037.307 us; speedup 1.0000x reference)
//
#include <hip/hip_runtime.h>
#include <hip/hip_bf16.h>
#include <math.h>

#define N_NODES 30000
#define N_EDGES 480000
#define N_GRAPH 64
#define DIN 24
#define HD 512
#define NL 6

typedef __hip_bfloat16 bf16;
using short8 = __attribute__((ext_vector_type(8))) short;
using f32x4 = __attribute__((ext_vector_type(4))) float;

// async 16B/lane global->LDS: lds dest = lp + lane*16 (wave-uniform lp!)
#define ASYNC16(gp, lp)                                              \
    __builtin_amdgcn_global_load_lds(                                \
        (const __attribute__((address_space(1))) void*)(gp),         \
        (__attribute__((address_space(3))) void*)(lp), 16, 0, 0)

// drain own vmem+lds ops, then rendezvous (buffer handoff point)
#define WAITALL_BAR()                                                \
    do {                                                             \
        asm volatile("s_waitcnt vmcnt(0) lgkmcnt(0)" ::: "memory");  \
        __builtin_amdgcn_sched_barrier(0);                           \
        __builtin_amdgcn_s_barrier();                                \
    } while (0)

__device__ __forceinline__ float sigmoidf_(float x) { return 1.0f / (1.0f + expf(-x)); }
__device__ __forceinline__ float b2f(unsigned short u) {
    return __uint_as_float(((unsigned int)u) << 16);
}
__device__ __forceinline__ unsigned short f2b(float f) {
    bf16 b = __float2bfloat16(f);
    return *(unsigned short*)&b;
}

// ---------------- encoder ---------------------------------------------------------
__global__ __launch_bounds__(256) void enc_kernel(const float* __restrict__ x,
                                                  const float* __restrict__ w,
                                                  const float* __restrict__ b,
                                                  bf16* __restrict__ h) {
    __shared__ float xs[DIN];
    int row = blockIdx.x;
    int tid = threadIdx.x;
    if (tid < DIN) xs[tid] = x[row * DIN + tid];
    __syncthreads();
    for (int c = tid; c < HD; c += 256) {
        float acc = b[c];
#pragma unroll
        for (int k = 0; k < DIN; k++) acc = fmaf(xs[k], w[k * HD + c], acc);
        h[(size_t)row * HD + c] = __float2bfloat16(acc);
    }
}

// ---------------- weight transpose + hi/lo split ----------------------------------
__global__ __launch_bounds__(256) void twcvt_kernel(const float* __restrict__ W,
                                                    bf16* __restrict__ WtH,
                                                    bf16* __restrict__ WtL, int Nc) {
    __shared__ float s[32][33];
    int l = blockIdx.z;
    const float* Wp = W + (size_t)l * HD * Nc;
    size_t ob = (size_t)l * HD * Nc;
    int k0 = blockIdx.y * 32, c0 = blockIdx.x * 32;
    int tx = threadIdx.x & 31, ty = threadIdx.x >> 5;
    for (int r = ty; r < 32; r += 8) s[r][tx] = Wp[(size_t)(k0 + r) * Nc + c0 + tx];
    __syncthreads();
    for (int r = ty; r < 32; r += 8) {
        float v = s[tx][r];
        unsigned short hu = f2b(v);
        float hf = b2f(hu);
        size_t o = ob + (size_t)(c0 + r) * HD + k0 + tx;
        *(unsigned short*)&WtH[o] = hu;
        WtL[o] = __float2bfloat16(v - hf);
    }
}

// ---------------- bf16 MFMA GEMM (hi/lo weights): tile 256x128 --------------------
// 512 thr = 8 waves (2 rowgroups x 4 colgroups). Double-buffer (64KB, 2 blocks/CU),
// one barrier per k-step. BM=256 halves per-row weight re-fetch (the R3 finding:
// staging bandwidth, dominated by weight re-streams, is the binding constraint).
template <bool RELU>
__global__ __launch_bounds__(512, 2) void gemm_mfma(const bf16* __restrict__ A,
                                                    const bf16* __restrict__ WtH,
                                                    const bf16* __restrict__ WtL,
                                                    const float* __restrict__ bias,
                                                    bf16* __restrict__ C, int n) {
    // per buffer (bf16 elems): A [0,8192), BH [8192,12288), BL [12288,16384)
    __shared__ __align__(16) bf16 SB[2][16384];
    int tid = threadIdx.x;
    int wv = tid >> 6, lane = tid & 63;
    int wr = wv >> 2, wc = wv & 3;
    int quad = lane >> 4, l16 = lane & 15;
    int crow = lane >> 2, cseg = lane & 3;
    int gseg = cseg ^ ((crow >> 1) & 3);          // 2-way-free swizzle
    int fsw = (quad ^ ((l16 >> 1) & 3)) * 8;
    int row0 = blockIdx.y * 256, col0 = blockIdx.x * 128;
    f32x4 acc[2][8] = {};

    // 32 staging chunks (A:0-15, BH:16-23, BL:24-31), 4 per wave
    const bf16* gsrc[4];
    int glds[4];
#pragma unroll
    for (int j = 0; j < 4; j++) {
        int c = wv * 4 + j;
        if (c < 16) {
            int gr = row0 + c * 16 + crow;
            if (gr > n - 1) gr = n - 1;           // clamp; dead rows guarded at write
            gsrc[j] = A + (size_t)gr * HD + gseg * 8;
            glds[j] = c * 512;
        } else if (c < 24) {
            gsrc[j] = WtH + (size_t)(col0 + (c - 16) * 16 + crow) * HD + gseg * 8;
            glds[j] = 8192 + (c - 16) * 512;
        } else {
            gsrc[j] = WtL + (size_t)(col0 + (c - 24) * 16 + crow) * HD + gseg * 8;
            glds[j] = 12288 + (c - 24) * 512;
        }
    }
    auto stage = [&](int kt, int nb) {
#pragma unroll
        for (int j = 0; j < 4; j++) ASYNC16(gsrc[j] + kt, &SB[nb][glds[j]]);
    };

    stage(0, 0);
    for (int t16 = 0; t16 < 16; t16++) {
        int b = t16 & 1;
        WAITALL_BAR();                            // tile t landed; prev buffer reads done
        if (t16 < 15) stage((t16 + 1) * 32, b ^ 1);
        short8 bfr[2][2];
#pragma unroll
        for (int t = 0; t < 2; t++) {
            int fo = ((wc * 2 + t) * 16 + l16) * 32 + fsw;
            bfr[t][0] = *(const short8*)&SB[b][8192 + fo];
            bfr[t][1] = *(const short8*)&SB[b][12288 + fo];
        }
        __builtin_amdgcn_s_setprio(1);
#pragma unroll
        for (int i = 0; i < 8; i++) {
            short8 af = *(const short8*)&SB[b][((wr * 8 + i) * 16 + l16) * 32 + fsw];
#pragma unroll
            for (int t = 0; t < 2; t++) {
                acc[t][i] = __builtin_amdgcn_mfma_f32_16x16x32_bf16(af, bfr[t][0], acc[t][i], 0, 0, 0);
                acc[t][i] = __builtin_amdgcn_mfma_f32_16x16x32_bf16(af, bfr[t][1], acc[t][i], 0, 0, 0);
            }
        }
        __builtin_amdgcn_s_setprio(0);
    }
    // ---- epilogue: two 128-row rounds, LDS-staged, coalesced 16B/lane writes ----
    __syncthreads();                              // all waves done with SB reads
    bf16* Cs = (bf16*)SB;                         // 128 x 132 (pad) = 33.8 KB
    const unsigned short* cp = (const unsigned short*)Cs;
#pragma unroll
    for (int h = 0; h < 2; h++) {
        if (wr == h) {
#pragma unroll
            for (int t = 0; t < 2; t++) {
                int colL = (wc * 2 + t) * 16 + l16;
                float bb = bias[col0 + colL];
#pragma unroll
                for (int i = 0; i < 8; i++) {
#pragma unroll
                    for (int r = 0; r < 4; r++) {
                        int rowL = i * 16 + quad * 4 + r;
                        float v = acc[t][i][r] + bb;
                        if (RELU) v = fmaxf(v, 0.0f);
                        Cs[rowL * 132 + colL] = __float2bfloat16(v);
                    }
                }
            }
        }
        __syncthreads();
#pragma unroll
        for (int pass = 0; pass < 4; pass++) {
            int rowL = pass * 32 + (tid >> 4);
            int row = row0 + h * 128 + rowL;
            int cc = (tid & 15) * 8;
            if (row < n) {
                ushort4 a0 = *(const ushort4*)&cp[rowL * 132 + cc];
                ushort4 a1 = *(const ushort4*)&cp[rowL * 132 + cc + 4];
                uint4 ov;
                ov.x = ((unsigned int)a0.y << 16) | a0.x;
                ov.y = ((unsigned int)a0.w << 16) | a0.z;
                ov.z = ((unsigned int)a1.y << 16) | a1.x;
                ov.w = ((unsigned int)a1.w << 16) | a1.z;
                *(uint4*)&((unsigned short*)C)[(size_t)row * HD + col0 + cc] = ov;
            }
        }
        __syncthreads();
    }
}

// ---------------- fused GRU (MFMA, hi/lo): tile 256r x 64c ------------------------
// 512 thr = 8 waves (2 rowgroups x 4 colgroups), each wave 128r x 16c. Single-buffer
// 80KB LDS -> 2 blocks/CU (16 waves/CU). BM=256 halves weight re-fetch (1.44->0.72GB).
// Epilogue: 4 x 64-row rounds, stage z,(1-z)*n f32 in retired Ws, coalesced RMW.
__global__ __launch_bounds__(512, 2) void gru_mfma(const bf16* __restrict__ M,
                                                   const bf16* __restrict__ Hc,
                                                   const bf16* __restrict__ WiH,
                                                   const bf16* __restrict__ WiL,
                                                   const bf16* __restrict__ WhH,
                                                   const bf16* __restrict__ WhL,
                                                   const float* __restrict__ bih,
                                                   const float* __restrict__ bhh,
                                                   bf16* __restrict__ Hn, int n) {
    __shared__ __align__(16) bf16 Ms[256 * 32];
    __shared__ __align__(16) bf16 Hs[256 * 32];
    __shared__ __align__(16) bf16 Ws[12 * 64 * 32];
    int tid = threadIdx.x;
    int wv = tid >> 6, lane = tid & 63;
    int wr = wv >> 2, wc = wv & 3;
    int quad = lane >> 4, l16 = lane & 15;
    int crow = lane >> 2, cseg = lane & 3;
    int gseg = cseg ^ ((crow >> 1) & 3);
    int fsw = (quad ^ ((l16 >> 1) & 3)) * 8;
    int row0 = blockIdx.y * 256, col0 = blockIdx.x * 64;
    f32x4 aR[8] = {}, aZ[8] = {}, aI[8] = {}, aHn[8] = {};

    // staging: wv0-3 -> M/H (8 chunks each); wv4-7 -> 12 weight panels (3 each)
    const bf16* mhsrc[8];
    bf16* mhdst[8];
    const bf16* wgp[3];
    int wldsb[3];
    if (wv < 4) {
        int mat = wv >> 1, half = wv & 1;
#pragma unroll
        for (int j = 0; j < 8; j++) {
            int ch = half * 8 + j;                // 0..15 row chunk
            int gr = row0 + ch * 16 + crow;
            if (gr > n - 1) gr = n - 1;
            mhsrc[j] = (mat ? Hc : M) + (size_t)gr * HD + gseg * 8;
            mhdst[j] = (mat ? Hs : Ms) + ch * 512;
        }
    } else {
        const bf16* wbase[4] = {WiH, WiL, WhH, WhL};
#pragma unroll
        for (int pp = 0; pp < 3; pp++) {
            int p = (wv - 4) * 3 + pp;            // 0..11
            int mat = (p >= 6);
            int q = p - mat * 6;
            int g = q >> 1, pl = q & 1;
            const bf16* base = wbase[mat * 2 + pl] + (size_t)(g * HD + col0) * HD;
            wgp[pp] = base + crow * HD + gseg * 8;
            wldsb[pp] = p * 2048;
        }
    }

    int fo = (wc * 16 + l16) * 32 + fsw;
    for (int kt = 0; kt < 512; kt += 32) {
        if (wv < 4) {
#pragma unroll
            for (int j = 0; j < 8; j++) ASYNC16(mhsrc[j] + kt, mhdst[j]);
        } else {
#pragma unroll
            for (int pp = 0; pp < 3; pp++)
#pragma unroll
                for (int s = 0; s < 4; s++)
                    ASYNC16(wgp[pp] + (size_t)s * 16 * HD + kt, &Ws[wldsb[pp] + s * 512]);
        }
        __syncthreads();
        short8 wrh = *(const short8*)&Ws[0 * 2048 + fo];
        short8 wrl = *(const short8*)&Ws[1 * 2048 + fo];
        short8 wzh = *(const short8*)&Ws[2 * 2048 + fo];
        short8 wzl = *(const short8*)&Ws[3 * 2048 + fo];
        short8 wnh = *(const short8*)&Ws[4 * 2048 + fo];
        short8 wnl = *(const short8*)&Ws[5 * 2048 + fo];
        short8 vrh = *(const short8*)&Ws[6 * 2048 + fo];
        short8 vrl = *(const short8*)&Ws[7 * 2048 + fo];
        short8 vzh = *(const short8*)&Ws[8 * 2048 + fo];
        short8 vzl = *(const short8*)&Ws[9 * 2048 + fo];
        short8 vnh = *(const short8*)&Ws[10 * 2048 + fo];
        short8 vnl = *(const short8*)&Ws[11 * 2048 + fo];
#pragma unroll
        for (int i = 0; i < 8; i++) {
            short8 am = *(const short8*)&Ms[((wr * 8 + i) * 16 + l16) * 32 + fsw];
            short8 ah = *(const short8*)&Hs[((wr * 8 + i) * 16 + l16) * 32 + fsw];
            aR[i] = __builtin_amdgcn_mfma_f32_16x16x32_bf16(am, wrh, aR[i], 0, 0, 0);
            aR[i] = __builtin_amdgcn_mfma_f32_16x16x32_bf16(am, wrl, aR[i], 0, 0, 0);
            aR[i] = __builtin_amdgcn_mfma_f32_16x16x32_bf16(ah, vrh, aR[i], 0, 0, 0);
            aR[i] = __builtin_amdgcn_mfma_f32_16x16x32_bf16(ah, vrl, aR[i], 0, 0, 0);
            aZ[i] = __builtin_amdgcn_mfma_f32_16x16x32_bf16(am, wzh, aZ[i], 0, 0, 0);
            aZ[i] = __builtin_amdgcn_mfma_f32_16x16x32_bf16(am, wzl, aZ[i], 0, 0, 0);
            aZ[i] = __builtin_amdgcn_mfma_f32_16x16x32_bf16(ah, vzh, aZ[i], 0, 0, 0);
            aZ[i] = __builtin_amdgcn_mfma_f32_16x16x32_bf16(ah, vzl, aZ[i], 0, 0, 0);
            aI[i] = __builtin_amdgcn_mfma_f32_16x16x32_bf16(am, wnh, aI[i], 0, 0, 0);
            aI[i] = __builtin_amdgcn_mfma_f32_16x16x32_bf16(am, wnl, aI[i], 0, 0, 0);
            aHn[i] = __builtin_amdgcn_mfma_f32_16x16x32_bf16(ah, vnh, aHn[i], 0, 0, 0);
            aHn[i] = __builtin_amdgcn_mfma_f32_16x16x32_bf16(ah, vnl, aHn[i], 0, 0, 0);
        }
        __syncthreads();
    }
    // ---- epilogue: 4 x 64-row rounds: gates -> LDS f32 -> coalesced RMW ----
    float* Zs32 = (float*)Ws;                     // [64][66] f32
    float* Ps32 = Zs32 + 64 * 66;                 // [64][66] f32 (33.8 KB total)
    int colL = wc * 16 + l16;
    int col = col0 + colL;
    float brz = bih[col] + bhh[col];
    float bzz = bih[HD + col] + bhh[HD + col];
    float bin_ = bih[2 * HD + col];
    float bhn_ = bhh[2 * HD + col];
    const unsigned short* hp = (const unsigned short*)Hc;
    unsigned short* op = (unsigned short*)Hn;
#pragma unroll
    for (int h = 0; h < 4; h++) {
        if (wr == (h >> 1)) {
            int ib = (h & 1) * 4;
#pragma unroll
            for (int i2 = 0; i2 < 4; i2++) {
                int i = ib + i2;
#pragma unroll
                for (int r = 0; r < 4; r++) {
                    int rowL = i2 * 16 + quad * 4 + r;  // 0..63 within round
                    float rg = sigmoidf_(aR[i][r] + brz);
                    float zg = sigmoidf_(aZ[i][r] + bzz);
                    float ng = tanhf(aI[i][r] + bin_ + rg * (aHn[i][r] + bhn_));
                    Zs32[rowL * 66 + colL] = zg;
                    Ps32[rowL * 66 + colL] = (1.0f - zg) * ng;
                }
            }
        }
        __syncthreads();
        {
            int rowL = tid >> 3;                  // 0..63
            int row = row0 + h * 64 + rowL;
            int cc = (tid & 7) * 8;
            if (row < n) {
                uint4 hv = *(const uint4*)&hp[(size_t)row * HD + col0 + cc];
                unsigned int hw[4] = {hv.x, hv.y, hv.z, hv.w};
                unsigned int ow[4];
#pragma unroll
                for (int q = 0; q < 4; q++) {
                    float h0 = b2f((unsigned short)(hw[q] & 0xffffu));
                    float h1 = b2f((unsigned short)(hw[q] >> 16));
                    float z0 = Zs32[rowL * 66 + cc + 2 * q];
                    float z1 = Zs32[rowL * 66 + cc + 2 * q + 1];
                    float p0 = Ps32[rowL * 66 + cc + 2 * q];
                    float p1 = Ps32[rowL * 66 + cc + 2 * q + 1];
                    float o0 = fmaf(z0, h0, p0);
                    float o1 = fmaf(z1, h1, p1);
                    ow[q] = ((unsigned int)f2b(o1) << 16) | f2b(o0);
                }
                uint4 ov = {ow[0], ow[1], ow[2], ow[3]};
                *(uint4*)&op[(size_t)row * HD + col0 + cc] = ov;
            }
        }
        __syncthreads();
    }
}

// ---------------- CSR build -------------------------------------------------------
__global__ __launch_bounds__(256) void deg_kernel(const int* __restrict__ dst,
                                                  int* __restrict__ deg) {
    int e = blockIdx.x * 256 + threadIdx.x;
    if (e < N_EDGES) atomicAdd(&deg[dst[e]], 1);
}

__global__ __launch_bounds__(1024) void scan_kernel(const int* __restrict__ deg,
                                                    int* __restrict__ offs) {
    __shared__ int buf[1024];
    __shared__ int carry_s;
    int tid = threadIdx.x;
    if (tid == 0) carry_s = 0;
    __syncthreads();
    for (int base = 0; base < N_NODES; base += 1024) {
        int v = (base + tid < N_NODES) ? deg[base + tid] : 0;
        buf[tid] = v;
        __syncthreads();
        for (int s = 1; s < 1024; s <<= 1) {
            int t = (tid >= s) ? buf[tid - s] : 0;
            __syncthreads();
            buf[tid] += t;
            __syncthreads();
        }
        int incl = buf[tid];
        if (base + tid < N_NODES) offs[base + tid] = carry_s + incl - v;
        __syncthreads();
        if (tid == 0) carry_s += buf[1023];
        __syncthreads();
    }
    if (tid == 0) offs[N_NODES] = carry_s;
}

__global__ __launch_bounds__(256) void bucket_kernel(const int* __restrict__ src,
                                                     const int* __restrict__ dst,
                                                     const int* __restrict__ offs,
                                                     int* __restrict__ cursor,
                                                     unsigned short* __restrict__ elist) {
    int e = blockIdx.x * 256 + threadIdx.x;
    if (e >= N_EDGES) return;
    int d = dst[e];
    int pos = atomicAdd(&cursor[d], 1);
    elist[offs[d] + pos] = (unsigned short)src[e];
}

// ---------------- gather-sum ------------------------------------------------------
__global__ __launch_bounds__(256) void gather_kernel(const bf16* __restrict__ msg,
                                                     bf16* __restrict__ m,
                                                     const unsigned short* __restrict__ elist,
                                                     const int* __restrict__ offs) {
    int nid = blockIdx.x, tid = threadIdx.x;
    int beg = offs[nid], end = offs[nid + 1];
    const unsigned int* mp = (const unsigned int*)msg;
    unsigned int u = mp[(size_t)nid * 256 + tid];
    float ax = b2f((unsigned short)(u & 0xffffu));
    float ay = b2f((unsigned short)(u >> 16));
    int e = beg;
    for (; e + 3 < end; e += 4) {
        unsigned int v0 = mp[(size_t)elist[e] * 256 + tid];
        unsigned int v1 = mp[(size_t)elist[e + 1] * 256 + tid];
        unsigned int v2 = mp[(size_t)elist[e + 2] * 256 + tid];
        unsigned int v3 = mp[(size_t)elist[e + 3] * 256 + tid];
        ax += b2f((unsigned short)(v0 & 0xffffu)) + b2f((unsigned short)(v1 & 0xffffu)) +
              b2f((unsigned short)(v2 & 0xffffu)) + b2f((unsigned short)(v3 & 0xffffu));
        ay += b2f((unsigned short)(v0 >> 16)) + b2f((unsigned short)(v1 >> 16)) +
              b2f((unsigned short)(v2 >> 16)) + b2f((unsigned short)(v3 >> 16));
    }
    for (; e < end; e++) {
        unsigned int v0 = mp[(size_t)elist[e] * 256 + tid];
        ax += b2f((unsigned short)(v0 & 0xffffu));
        ay += b2f((unsigned short)(v0 >> 16));
    }
    unsigned int out = ((unsigned int)f2b(ay) << 16) | (unsigned int)f2b(ax);
    ((unsigned int*)m)[(size_t)nid * 256 + tid] = out;
}

// ---------------- pooling (segmented, batch sorted -> no atomics) -----------------
__global__ __launch_bounds__(256) void pool_kernel(const bf16* __restrict__ h,
                                                   const int* __restrict__ batch,
                                                   float* __restrict__ pooled,
                                                   float* __restrict__ cnt) {
    int g = blockIdx.x;
    int col = blockIdx.y * 256 + threadIdx.x;
    // lower_bound for g and g+1 in sorted batch
    int lo = 0, hi = N_NODES;
    while (lo < hi) { int mid = (lo + hi) >> 1; if (batch[mid] < g) lo = mid + 1; else hi = mid; }
    int gs = lo;
    hi = N_NODES;
    while (lo < hi) { int mid = (lo + hi) >> 1; if (batch[mid] < g + 1) lo = mid + 1; else hi = mid; }
    int ge = lo;
    const unsigned short* hp = (const unsigned short*)h;
    float acc = 0.0f;
    int r = gs;
    for (; r + 3 < ge; r += 4) {
        acc += b2f(hp[(size_t)r * HD + col]) + b2f(hp[(size_t)(r + 1) * HD + col]) +
               b2f(hp[(size_t)(r + 2) * HD + col]) + b2f(hp[(size_t)(r + 3) * HD + col]);
    }
    for (; r < ge; r++) acc += b2f(hp[(size_t)r * HD + col]);
    pooled[g * HD + col] = acc;
    if (blockIdx.y == 0 && threadIdx.x == 0) cnt[g] = (float)(ge - gs);
}

__global__ __launch_bounds__(256) void head_kernel(const float* __restrict__ pooled,
                                                   const float* __restrict__ cnt,
                                                   const float* __restrict__ w1,
                                                   const float* __restrict__ b1,
                                                   const float* __restrict__ w2,
                                                   const float* __restrict__ b2,
                                                   float* __restrict__ out) {
    __shared__ float prow[HD];
    __shared__ float red[256];
    int g = blockIdx.x, tid = threadIdx.x;
    float c = fmaxf(cnt[g], 1.0f);
    for (int j = tid; j < HD; j += 256) prow[j] = pooled[g * HD + j] / c;
    __syncthreads();
    float acc = b1[tid];
    for (int k = 0; k < HD; k++) acc = fmaf(prow[k], w1[k * 256 + tid], acc);
    red[tid] = fmaxf(acc, 0.0f) * w2[tid];
    __syncthreads();
    for (int s = 128; s > 0; s >>= 1) {
        if (tid < s) red[tid] += red[tid + s];
        __syncthreads();
    }
    if (tid == 0) out[g] = red[0] + b2[0];
}

// ---------------- launch ----------------------------------------------------------
extern "C" void kernel_launch(void* const* d_in, const int* in_sizes, int n_in,
                              void* d_out, int out_size, void* d_ws, size_t ws_size,
                              hipStream_t stream) {
    const float* x = (const float*)d_in[0];
    const int* eidx = (const int*)d_in[1];
    const int* batch = (const int*)d_in[2];
    const float* enc_w = (const float*)d_in[3];
    const float* enc_b = (const float*)d_in[4];
    const float* mlp_w1 = (const float*)d_in[5];
    const float* mlp_b1 = (const float*)d_in[6];
    const float* mlp_w2 = (const float*)d_in[7];
    const float* mlp_b2 = (const float*)d_in[8];
    const float* gru_wih = (const float*)d_in[9];
    const float* gru_whh = (const float*)d_in[10];
    const float* gru_bih = (const float*)d_in[11];
    const float* gru_bhh = (const float*)d_in[12];
    const float* head_w1 = (const float*)d_in[13];
    const float* head_b1 = (const float*)d_in[14];
    const float* head_w2 = (const float*)d_in[15];
    const float* head_b2 = (const float*)d_in[16];
    const int* src = eidx;
    const int* dst = eidx + N_EDGES;

    const size_t NH = (size_t)N_NODES * HD;
    char* p = (char*)d_ws;
    auto alloc = [&](size_t bytes) { char* q = p; p += (bytes + 255) & ~(size_t)255; return q; };
    bf16* S0 = (bf16*)alloc(NH * 2);
    bf16* S1 = (bf16*)alloc(NH * 2);
    bf16* S2 = (bf16*)alloc(NH * 2);
    bf16* w1tH = (bf16*)alloc((size_t)NL * HD * HD * 2);
    bf16* w1tL = (bf16*)alloc((size_t)NL * HD * HD * 2);
    bf16* w2tH = (bf16*)alloc((size_t)NL * HD * HD * 2);
    bf16* w2tL = (bf16*)alloc((size_t)NL * HD * HD * 2);
    bf16* wihtH = (bf16*)alloc((size_t)NL * 3 * HD * HD * 2);
    bf16* wihtL = (bf16*)alloc((size_t)NL * 3 * HD * HD * 2);
    bf16* whhtH = (bf16*)alloc((size_t)NL * 3 * HD * HD * 2);
    bf16* whhtL = (bf16*)alloc((size_t)NL * 3 * HD * HD * 2);
    float* pooled = (float*)alloc((size_t)N_GRAPH * HD * 4);
    float* cnt = (float*)alloc(N_GRAPH * 4);
    int* deg = (int*)alloc((N_NODES + 1) * 4);  // also cursor
    int* offs = (int*)alloc((N_NODES + 1) * 4);
    unsigned short* elist = (unsigned short*)alloc((size_t)N_EDGES * 2);
    // total ~144 MB (proven-safe envelope)

    twcvt_kernel<<<dim3(16, 16, NL), 256, 0, stream>>>(mlp_w1, w1tH, w1tL, HD);
    twcvt_kernel<<<dim3(16, 16, NL), 256, 0, stream>>>(mlp_w2, w2tH, w2tL, HD);
    twcvt_kernel<<<dim3(48, 16, NL), 256, 0, stream>>>(gru_wih, wihtH, wihtL, 3 * HD);
    twcvt_kernel<<<dim3(48, 16, NL), 256, 0, stream>>>(gru_whh, whhtH, whhtL, 3 * HD);

    hipMemsetAsync(deg, 0, (N_NODES + 1) * sizeof(int), stream);
    deg_kernel<<<(N_EDGES + 255) / 256, 256, 0, stream>>>(dst, deg);
    scan_kernel<<<1, 1024, 0, stream>>>(deg, offs);
    hipMemsetAsync(deg, 0, (N_NODES + 1) * sizeof(int), stream);
    bucket_kernel<<<(N_EDGES + 255) / 256, 256, 0, stream>>>(src, dst, offs, deg, elist);

    enc_kernel<<<N_NODES, 256, 0, stream>>>(x, enc_w, enc_b, S0);

    bf16* hcur = S0;
    bf16* hoth = S1;
    dim3 ggrid(4, (N_NODES + 255) / 256);   // 256-row x 128-col tiles
    dim3 ugrid(8, (N_NODES + 255) / 256);   // 256-row x 64-col tiles

    for (int l = 0; l < NL; l++) {
        size_t wsq = (size_t)l * HD * HD;
        size_t wgq = (size_t)l * 3 * HD * HD;
        const float* b1 = mlp_b1 + (size_t)l * HD;
        const float* b2 = mlp_b2 + (size_t)l * HD;
        const float* bih = gru_bih + (size_t)l * 3 * HD;
        const float* bhh = gru_bhh + (size_t)l * 3 * HD;

        gemm_mfma<true><<<ggrid, 512, 0, stream>>>(hcur, w1tH + wsq, w1tL + wsq, b1, hoth, N_NODES);
        gemm_mfma<false><<<ggrid, 512, 0, stream>>>(hoth, w2tH + wsq, w2tL + wsq, b2, S2, N_NODES);
        gather_kernel<<<N_NODES, 256, 0, stream>>>(S2, hoth, elist, offs);
        gru_mfma<<<ugrid, 512, 0, stream>>>(hoth, hcur, wihtH + wgq, wihtL + wgq,
                                            whhtH + wgq, whhtL + wgq, bih, bhh, S2, N_NODES);
        bf16* newh = S2;
        S2 = hcur;
        hcur = newh;
    }

    pool_kernel<<<dim3(N_GRAPH, 2), 256, 0, stream>>>(hcur, batch, pooled, cnt);
    head_kernel<<<N_GRAPH, 256, 0, stream>>>(pooled, cnt, head_w1, head_b1, head_w2, head_b2,
                                             (float*)d_out);
}

// Round 6
// 2406.240 us; speedup vs baseline: 1.2623x; 1.2623x over previous
//
#include <hip/hip_runtime.h>
#include <hip/hip_bf16.h>
#include <math.h>

#define N_NODES 30000
#define N_EDGES 480000
#define N_GRAPH 64
#define DIN 24
#define HD 512
#define NL 6
#define NRG 235   // ceil(30000/128) row-groups

typedef __hip_bfloat16 bf16;
using short8 = __attribute__((ext_vector_type(8))) short;
using f32x4 = __attribute__((ext_vector_type(4))) float;

// async 16B/lane global->LDS: lds dest = lp + lane*16 (wave-uniform lp!)
#define ASYNC16(gp, lp)                                              \
    __builtin_amdgcn_global_load_lds(                                \
        (const __attribute__((address_space(1))) void*)(gp),         \
        (__attribute__((address_space(3))) void*)(lp), 16, 0, 0)

__device__ __forceinline__ float sigmoidf_(float x) { return 1.0f / (1.0f + expf(-x)); }
__device__ __forceinline__ float b2f(unsigned short u) {
    return __uint_as_float(((unsigned int)u) << 16);
}
__device__ __forceinline__ unsigned short f2b(float f) {
    bf16 b = __float2bfloat16(f);
    return *(unsigned short*)&b;
}

// ---------------- encoder ---------------------------------------------------------
__global__ __launch_bounds__(256) void enc_kernel(const float* __restrict__ x,
                                                  const float* __restrict__ w,
                                                  const float* __restrict__ b,
                                                  bf16* __restrict__ h) {
    __shared__ float xs[DIN];
    int row = blockIdx.x;
    int tid = threadIdx.x;
    if (tid < DIN) xs[tid] = x[row * DIN + tid];
    __syncthreads();
    for (int c = tid; c < HD; c += 256) {
        float acc = b[c];
#pragma unroll
        for (int k = 0; k < DIN; k++) acc = fmaf(xs[k], w[k * HD + c], acc);
        h[(size_t)row * HD + c] = __float2bfloat16(acc);
    }
}

// ---------------- weight transpose + hi/lo split ----------------------------------
__global__ __launch_bounds__(256) void twcvt_kernel(const float* __restrict__ W,
                                                    bf16* __restrict__ WtH,
                                                    bf16* __restrict__ WtL, int Nc) {
    __shared__ float s[32][33];
    int l = blockIdx.z;
    const float* Wp = W + (size_t)l * HD * Nc;
    size_t ob = (size_t)l * HD * Nc;
    int k0 = blockIdx.y * 32, c0 = blockIdx.x * 32;
    int tx = threadIdx.x & 31, ty = threadIdx.x >> 5;
    for (int r = ty; r < 32; r += 8) s[r][tx] = Wp[(size_t)(k0 + r) * Nc + c0 + tx];
    __syncthreads();
    for (int r = ty; r < 32; r += 8) {
        float v = s[tx][r];
        unsigned short hu = f2b(v);
        float hf = b2f(hu);
        size_t o = ob + (size_t)(c0 + r) * HD + k0 + tx;
        *(unsigned short*)&WtH[o] = hu;
        WtL[o] = __float2bfloat16(v - hf);
    }
}

// ---------------- bf16 MFMA GEMM (hi/lo weights): tile 128x128 --------------------
// 4 waves col-split (wave owns 128r x 32c). Single-buffer loop; A staged 128B/row
// every other k-step (full-line utilization); XCD-banded 1-D grid: each XCD gets
// 1/8 of row-groups x all 4 col-slices (W L2-resident, A fetched once per XCD).
template <bool RELU>
__global__ __launch_bounds__(256, 4) void gemm_mfma(const bf16* __restrict__ A,
                                                    const bf16* __restrict__ WtH,
                                                    const bf16* __restrict__ WtL,
                                                    const float* __restrict__ bias,
                                                    bf16* __restrict__ C, int n) {
    // GS: As [0,8192) (128rx64k), BH [8192,12288), BL [12288,16384); epilogue Cs 16896
    __shared__ __align__(16) bf16 GS[16896];
    int id = blockIdx.x;
    int xcd = id & 7, kb = id >> 3;
    int bx = kb & 3;
    int by = (kb >> 2) * 8 + xcd;
    if (by >= (n + 127) / 128) return;
    int row0 = by * 128, col0 = bx * 128;

    int tid = threadIdx.x;
    int wv = tid >> 6, lane = tid & 63;
    int quad = lane >> 4, l16 = lane & 15;
    int crow = lane >> 2, cseg = lane & 3;
    int gseg = cseg ^ ((crow >> 1) & 3);          // B-side 2-bit swizzle (64B rows)
    int fsw = (quad ^ ((l16 >> 1) & 3)) * 8;
    // A-side 3-bit swizzle (128B rows)
    int r7 = lane >> 3, s3 = lane & 7;
    int keyr = ((r7 & 1) << 2) | ((r7 >> 1) & 3);
    int sseg = s3 ^ keyr;
    int mkey = ((l16 & 1) << 2) | ((l16 >> 1) & 3);
    f32x4 acc[2][8] = {};

    // A row offsets: wv0 chunks 0-7, wv1 chunks 8-15 (8 rows x 128B each)
    int gro[8];
    if (wv < 2) {
#pragma unroll
        for (int j = 0; j < 8; j++) {
            int c = wv * 8 + j;
            int gr = row0 + c * 8 + r7;
            if (gr > n - 1) gr = n - 1;
            gro[j] = gr * HD + sseg * 8;
        }
    } else {
        const bf16* wb = (wv == 2) ? WtH : WtL;
#pragma unroll
        for (int j = 0; j < 8; j++)
            gro[j] = 0;                           // unused
#pragma unroll
        for (int s = 0; s < 8; s++) { }
    }
    int boff[8];
    const bf16* wb = (wv == 2) ? WtH : WtL;
    if (wv >= 2) {
#pragma unroll
        for (int s = 0; s < 8; s++) boff[s] = (col0 + s * 16 + crow) * HD + gseg * 8;
    }
    bf16* bdst = GS + ((wv == 2) ? 8192 : 12288);

    for (int kt = 0; kt < 512; kt += 32) {
        int kk = (kt >> 5) & 1;
        if (wv < 2) {
            if (kk == 0) {
#pragma unroll
                for (int j = 0; j < 8; j++)
                    ASYNC16(&A[gro[j] + kt], &GS[(wv * 8 + j) * 512]);
            }
        } else {
#pragma unroll
            for (int s = 0; s < 8; s++) ASYNC16(&wb[boff[s] + kt], &bdst[s * 512]);
        }
        __syncthreads();
        short8 bfr[2][2];
#pragma unroll
        for (int t = 0; t < 2; t++) {
            int fo = ((wv * 2 + t) * 16 + l16) * 32 + fsw;
            bfr[t][0] = *(const short8*)&GS[8192 + fo];
            bfr[t][1] = *(const short8*)&GS[12288 + fo];
        }
        int aoffk = (((kk << 2) + quad) ^ mkey) * 8;
        __builtin_amdgcn_s_setprio(1);
#pragma unroll
        for (int i = 0; i < 8; i++) {
            short8 af = *(const short8*)&GS[(i * 16 + l16) * 64 + aoffk];
#pragma unroll
            for (int t = 0; t < 2; t++) {
                acc[t][i] = __builtin_amdgcn_mfma_f32_16x16x32_bf16(af, bfr[t][0], acc[t][i], 0, 0, 0);
                acc[t][i] = __builtin_amdgcn_mfma_f32_16x16x32_bf16(af, bfr[t][1], acc[t][i], 0, 0, 0);
            }
        }
        __builtin_amdgcn_s_setprio(0);
        __syncthreads();
    }
    // ---- epilogue: stage bf16 tile in LDS, then coalesced 16B/lane writes ----
    bf16* Cs = GS;                                // 128 x 132 (pad) = 33 KB
#pragma unroll
    for (int t = 0; t < 2; t++) {
        int colL = (wv * 2 + t) * 16 + l16;
        float bb = bias[col0 + colL];
#pragma unroll
        for (int i = 0; i < 8; i++) {
#pragma unroll
            for (int r = 0; r < 4; r++) {
                int rowL = i * 16 + quad * 4 + r;
                float v = acc[t][i][r] + bb;
                if (RELU) v = fmaxf(v, 0.0f);
                Cs[rowL * 132 + colL] = __float2bfloat16(v);
            }
        }
    }
    __syncthreads();
    const unsigned short* cp = (const unsigned short*)Cs;
#pragma unroll
    for (int pass = 0; pass < 8; pass++) {
        int rowL = pass * 16 + (tid >> 4);
        int row = row0 + rowL;
        int cc = (tid & 15) * 8;
        if (row < n) {
            ushort4 a0 = *(const ushort4*)&cp[rowL * 132 + cc];
            ushort4 a1 = *(const ushort4*)&cp[rowL * 132 + cc + 4];
            uint4 ov;
            ov.x = ((unsigned int)a0.y << 16) | a0.x;
            ov.y = ((unsigned int)a0.w << 16) | a0.z;
            ov.z = ((unsigned int)a1.y << 16) | a1.x;
            ov.w = ((unsigned int)a1.w << 16) | a1.z;
            *(uint4*)&((unsigned short*)C)[(size_t)row * HD + col0 + cc] = ov;
        }
    }
}

// ---------------- fused GRU (MFMA, hi/lo, col-split waves) ------------------------
// tile 128r x 64c, 4 waves each own 128r x 16c. Single-buffer (80KB, 2 blocks/CU).
// M/H staged 128B/row every other k-step; XCD-banded grid: each XCD = 1/4 rows x
// 4 col-slices (M/H fetched once per row-band, W 3MB L2-resident).
__global__ __launch_bounds__(256, 2) void gru_mfma(const bf16* __restrict__ M,
                                                   const bf16* __restrict__ Hc,
                                                   const bf16* __restrict__ WiH,
                                                   const bf16* __restrict__ WiL,
                                                   const bf16* __restrict__ WhH,
                                                   const bf16* __restrict__ WhL,
                                                   const float* __restrict__ bih,
                                                   const float* __restrict__ bhh,
                                                   bf16* __restrict__ Hn, int n) {
    __shared__ __align__(16) bf16 Ms[128 * 64];
    __shared__ __align__(16) bf16 Hs[128 * 64];
    __shared__ __align__(16) bf16 Ws[12 * 64 * 32];
    int id = blockIdx.x;
    int xcd = id & 7, kb = id >> 3;
    int band = xcd >> 1, colg = xcd & 1;
    int bx = colg * 4 + (kb & 3);
    int by = (kb >> 2) * 4 + band;
    if (by >= (n + 127) / 128) return;
    int row0 = by * 128, col0 = bx * 64;

    int tid = threadIdx.x;
    int wv = tid >> 6, lane = tid & 63;
    int quad = lane >> 4, l16 = lane & 15;
    int crow = lane >> 2, cseg = lane & 3;
    int gseg = cseg ^ ((crow >> 1) & 3);
    int fsw = (quad ^ ((l16 >> 1) & 3)) * 8;
    int r7 = lane >> 3, s3 = lane & 7;
    int keyr = ((r7 & 1) << 2) | ((r7 >> 1) & 3);
    int sseg = s3 ^ keyr;
    int mkey = ((l16 & 1) << 2) | ((l16 >> 1) & 3);
    f32x4 aR[8] = {}, aZ[8] = {}, aI[8] = {}, aHn[8] = {};

    int gro[16];
    const bf16* wgp[4];
    int wlds[4];
    if (wv == 0) {
#pragma unroll
        for (int c = 0; c < 16; c++) {
            int gr = row0 + c * 8 + r7;
            if (gr > n - 1) gr = n - 1;
            gro[c] = gr * HD + sseg * 8;
        }
    } else {
        const bf16* wbase[4] = {WiH, WiL, WhH, WhL};
#pragma unroll
        for (int pp = 0; pp < 4; pp++) {
            int p = (wv - 1) * 4 + pp;            // 0..11
            int mat = (p >= 6);
            int q = p - mat * 6;
            int g = q >> 1, pl = q & 1;
            const bf16* base = wbase[mat * 2 + pl] + (size_t)(g * HD + col0) * HD;
            wgp[pp] = base + crow * HD + gseg * 8;
            wlds[pp] = p * 2048;
        }
    }

    int fo = (wv * 16 + l16) * 32 + fsw;
    for (int kt = 0; kt < 512; kt += 32) {
        int kk = (kt >> 5) & 1;
        if (wv == 0) {
            if (kk == 0) {
#pragma unroll
                for (int c = 0; c < 16; c++) {
                    ASYNC16(&M[gro[c] + kt], &Ms[c * 512]);
                    ASYNC16(&Hc[gro[c] + kt], &Hs[c * 512]);
                }
            }
        } else {
#pragma unroll
            for (int pp = 0; pp < 4; pp++)
#pragma unroll
                for (int s = 0; s < 4; s++)
                    ASYNC16(wgp[pp] + (size_t)s * 16 * HD + kt, &Ws[wlds[pp] + s * 512]);
        }
        __syncthreads();
        short8 wrh = *(const short8*)&Ws[0 * 2048 + fo];
        short8 wrl = *(const short8*)&Ws[1 * 2048 + fo];
        short8 wzh = *(const short8*)&Ws[2 * 2048 + fo];
        short8 wzl = *(const short8*)&Ws[3 * 2048 + fo];
        short8 wnh = *(const short8*)&Ws[4 * 2048 + fo];
        short8 wnl = *(const short8*)&Ws[5 * 2048 + fo];
        short8 vrh = *(const short8*)&Ws[6 * 2048 + fo];
        short8 vrl = *(const short8*)&Ws[7 * 2048 + fo];
        short8 vzh = *(const short8*)&Ws[8 * 2048 + fo];
        short8 vzl = *(const short8*)&Ws[9 * 2048 + fo];
        short8 vnh = *(const short8*)&Ws[10 * 2048 + fo];
        short8 vnl = *(const short8*)&Ws[11 * 2048 + fo];
        int aoffk = (((kk << 2) + quad) ^ mkey) * 8;
        __builtin_amdgcn_s_setprio(1);
#pragma unroll
        for (int i = 0; i < 8; i++) {
            short8 am = *(const short8*)&Ms[(i * 16 + l16) * 64 + aoffk];
            short8 ah = *(const short8*)&Hs[(i * 16 + l16) * 64 + aoffk];
            aR[i] = __builtin_amdgcn_mfma_f32_16x16x32_bf16(am, wrh, aR[i], 0, 0, 0);
            aR[i] = __builtin_amdgcn_mfma_f32_16x16x32_bf16(am, wrl, aR[i], 0, 0, 0);
            aR[i] = __builtin_amdgcn_mfma_f32_16x16x32_bf16(ah, vrh, aR[i], 0, 0, 0);
            aR[i] = __builtin_amdgcn_mfma_f32_16x16x32_bf16(ah, vrl, aR[i], 0, 0, 0);
            aZ[i] = __builtin_amdgcn_mfma_f32_16x16x32_bf16(am, wzh, aZ[i], 0, 0, 0);
            aZ[i] = __builtin_amdgcn_mfma_f32_16x16x32_bf16(am, wzl, aZ[i], 0, 0, 0);
            aZ[i] = __builtin_amdgcn_mfma_f32_16x16x32_bf16(ah, vzh, aZ[i], 0, 0, 0);
            aZ[i] = __builtin_amdgcn_mfma_f32_16x16x32_bf16(ah, vzl, aZ[i], 0, 0, 0);
            aI[i] = __builtin_amdgcn_mfma_f32_16x16x32_bf16(am, wnh, aI[i], 0, 0, 0);
            aI[i] = __builtin_amdgcn_mfma_f32_16x16x32_bf16(am, wnl, aI[i], 0, 0, 0);
            aHn[i] = __builtin_amdgcn_mfma_f32_16x16x32_bf16(ah, vnh, aHn[i], 0, 0, 0);
            aHn[i] = __builtin_amdgcn_mfma_f32_16x16x32_bf16(ah, vnl, aHn[i], 0, 0, 0);
        }
        __builtin_amdgcn_s_setprio(0);
        __syncthreads();
    }
    // ---- epilogue: gates -> stage z, (1-z)*n (f32, halves) -> coalesced RMW ----
    float* Zs32 = (float*)Ws;                     // [64][66] f32
    float* Ps32 = Zs32 + 64 * 66;                 // [64][66] f32 (33.8 KB total)
    int colL = wv * 16 + l16;
    int col = col0 + colL;
    float brz = bih[col] + bhh[col];
    float bzz = bih[HD + col] + bhh[HD + col];
    float bin_ = bih[2 * HD + col];
    float bhn_ = bhh[2 * HD + col];
    const unsigned short* hp = (const unsigned short*)Hc;
    unsigned short* op = (unsigned short*)Hn;
#pragma unroll
    for (int hhalf = 0; hhalf < 2; hhalf++) {
#pragma unroll
        for (int i = 0; i < 4; i++) {
            int ii = hhalf * 4 + i;
#pragma unroll
            for (int r = 0; r < 4; r++) {
                int rowL = i * 16 + quad * 4 + r;  // 0..63 within half
                float rg = sigmoidf_(aR[ii][r] + brz);
                float zg = sigmoidf_(aZ[ii][r] + bzz);
                float ng = tanhf(aI[ii][r] + bin_ + rg * (aHn[ii][r] + bhn_));
                Zs32[rowL * 66 + colL] = zg;
                Ps32[rowL * 66 + colL] = (1.0f - zg) * ng;
            }
        }
        __syncthreads();
#pragma unroll
        for (int sub = 0; sub < 2; sub++) {
            int rowL = sub * 32 + (tid >> 3);
            int row = row0 + hhalf * 64 + rowL;
            int cc = (tid & 7) * 8;
            if (row < n) {
                uint4 hv = *(const uint4*)&hp[(size_t)row * HD + col0 + cc];
                unsigned int hw[4] = {hv.x, hv.y, hv.z, hv.w};
                unsigned int ow[4];
#pragma unroll
                for (int q = 0; q < 4; q++) {
                    float h0 = b2f((unsigned short)(hw[q] & 0xffffu));
                    float h1 = b2f((unsigned short)(hw[q] >> 16));
                    float z0 = Zs32[rowL * 66 + cc + 2 * q];
                    float z1 = Zs32[rowL * 66 + cc + 2 * q + 1];
                    float p0 = Ps32[rowL * 66 + cc + 2 * q];
                    float p1 = Ps32[rowL * 66 + cc + 2 * q + 1];
                    float o0 = fmaf(z0, h0, p0);
                    float o1 = fmaf(z1, h1, p1);
                    ow[q] = ((unsigned int)f2b(o1) << 16) | f2b(o0);
                }
                uint4 ov = {ow[0], ow[1], ow[2], ow[3]};
                *(uint4*)&op[(size_t)row * HD + col0 + cc] = ov;
            }
        }
        __syncthreads();
    }
}

// ---------------- CSR build -------------------------------------------------------
__global__ __launch_bounds__(256) void deg_kernel(const int* __restrict__ dst,
                                                  int* __restrict__ deg) {
    int e = blockIdx.x * 256 + threadIdx.x;
    if (e < N_EDGES) atomicAdd(&deg[dst[e]], 1);
}

__global__ __launch_bounds__(1024) void scan_kernel(const int* __restrict__ deg,
                                                    int* __restrict__ offs) {
    __shared__ int buf[1024];
    __shared__ int carry_s;
    int tid = threadIdx.x;
    if (tid == 0) carry_s = 0;
    __syncthreads();
    for (int base = 0; base < N_NODES; base += 1024) {
        int v = (base + tid < N_NODES) ? deg[base + tid] : 0;
        buf[tid] = v;
        __syncthreads();
        for (int s = 1; s < 1024; s <<= 1) {
            int t = (tid >= s) ? buf[tid - s] : 0;
            __syncthreads();
            buf[tid] += t;
            __syncthreads();
        }
        int incl = buf[tid];
        if (base + tid < N_NODES) offs[base + tid] = carry_s + incl - v;
        __syncthreads();
        if (tid == 0) carry_s += buf[1023];
        __syncthreads();
    }
    if (tid == 0) offs[N_NODES] = carry_s;
}

__global__ __launch_bounds__(256) void bucket_kernel(const int* __restrict__ src,
                                                     const int* __restrict__ dst,
                                                     const int* __restrict__ offs,
                                                     int* __restrict__ cursor,
                                                     unsigned short* __restrict__ elist) {
    int e = blockIdx.x * 256 + threadIdx.x;
    if (e >= N_EDGES) return;
    int d = dst[e];
    int pos = atomicAdd(&cursor[d], 1);
    elist[offs[d] + pos] = (unsigned short)src[e];
}

// ---------------- gather-sum ------------------------------------------------------
__global__ __launch_bounds__(256) void gather_kernel(const bf16* __restrict__ msg,
                                                     bf16* __restrict__ m,
                                                     const unsigned short* __restrict__ elist,
                                                     const int* __restrict__ offs) {
    int nid = blockIdx.x, tid = threadIdx.x;
    int beg = offs[nid], end = offs[nid + 1];
    const unsigned int* mp = (const unsigned int*)msg;
    unsigned int u = mp[(size_t)nid * 256 + tid];
    float ax = b2f((unsigned short)(u & 0xffffu));
    float ay = b2f((unsigned short)(u >> 16));
    int e = beg;
    for (; e + 3 < end; e += 4) {
        unsigned int v0 = mp[(size_t)elist[e] * 256 + tid];
        unsigned int v1 = mp[(size_t)elist[e + 1] * 256 + tid];
        unsigned int v2 = mp[(size_t)elist[e + 2] * 256 + tid];
        unsigned int v3 = mp[(size_t)elist[e + 3] * 256 + tid];
        ax += b2f((unsigned short)(v0 & 0xffffu)) + b2f((unsigned short)(v1 & 0xffffu)) +
              b2f((unsigned short)(v2 & 0xffffu)) + b2f((unsigned short)(v3 & 0xffffu));
        ay += b2f((unsigned short)(v0 >> 16)) + b2f((unsigned short)(v1 >> 16)) +
              b2f((unsigned short)(v2 >> 16)) + b2f((unsigned short)(v3 >> 16));
    }
    for (; e < end; e++) {
        unsigned int v0 = mp[(size_t)elist[e] * 256 + tid];
        ax += b2f((unsigned short)(v0 & 0xffffu));
        ay += b2f((unsigned short)(v0 >> 16));
    }
    unsigned int out = ((unsigned int)f2b(ay) << 16) | (unsigned int)f2b(ax);
    ((unsigned int*)m)[(size_t)nid * 256 + tid] = out;
}

// ---------------- pooling (segmented, batch sorted -> no atomics) -----------------
__global__ __launch_bounds__(256) void pool_kernel(const bf16* __restrict__ h,
                                                   const int* __restrict__ batch,
                                                   float* __restrict__ pooled,
                                                   float* __restrict__ cnt) {
    int g = blockIdx.x;
    int col = blockIdx.y * 256 + threadIdx.x;
    // lower_bound for g and g+1 in sorted batch
    int lo = 0, hi = N_NODES;
    while (lo < hi) { int mid = (lo + hi) >> 1; if (batch[mid] < g) lo = mid + 1; else hi = mid; }
    int gs = lo;
    hi = N_NODES;
    while (lo < hi) { int mid = (lo + hi) >> 1; if (batch[mid] < g + 1) lo = mid + 1; else hi = mid; }
    int ge = lo;
    const unsigned short* hp = (const unsigned short*)h;
    float acc = 0.0f;
    int r = gs;
    for (; r + 3 < ge; r += 4) {
        acc += b2f(hp[(size_t)r * HD + col]) + b2f(hp[(size_t)(r + 1) * HD + col]) +
               b2f(hp[(size_t)(r + 2) * HD + col]) + b2f(hp[(size_t)(r + 3) * HD + col]);
    }
    for (; r < ge; r++) acc += b2f(hp[(size_t)r * HD + col]);
    pooled[g * HD + col] = acc;
    if (blockIdx.y == 0 && threadIdx.x == 0) cnt[g] = (float)(ge - gs);
}

__global__ __launch_bounds__(256) void head_kernel(const float* __restrict__ pooled,
                                                   const float* __restrict__ cnt,
                                                   const float* __restrict__ w1,
                                                   const float* __restrict__ b1,
                                                   const float* __restrict__ w2,
                                                   const float* __restrict__ b2,
                                                   float* __restrict__ out) {
    __shared__ float prow[HD];
    __shared__ float red[256];
    int g = blockIdx.x, tid = threadIdx.x;
    float c = fmaxf(cnt[g], 1.0f);
    for (int j = tid; j < HD; j += 256) prow[j] = pooled[g * HD + j] / c;
    __syncthreads();
    float acc = b1[tid];
    for (int k = 0; k < HD; k++) acc = fmaf(prow[k], w1[k * 256 + tid], acc);
    red[tid] = fmaxf(acc, 0.0f) * w2[tid];
    __syncthreads();
    for (int s = 128; s > 0; s >>= 1) {
        if (tid < s) red[tid] += red[tid + s];
        __syncthreads();
    }
    if (tid == 0) out[g] = red[0] + b2[0];
}

// ---------------- launch ----------------------------------------------------------
extern "C" void kernel_launch(void* const* d_in, const int* in_sizes, int n_in,
                              void* d_out, int out_size, void* d_ws, size_t ws_size,
                              hipStream_t stream) {
    const float* x = (const float*)d_in[0];
    const int* eidx = (const int*)d_in[1];
    const int* batch = (const int*)d_in[2];
    const float* enc_w = (const float*)d_in[3];
    const float* enc_b = (const float*)d_in[4];
    const float* mlp_w1 = (const float*)d_in[5];
    const float* mlp_b1 = (const float*)d_in[6];
    const float* mlp_w2 = (const float*)d_in[7];
    const float* mlp_b2 = (const float*)d_in[8];
    const float* gru_wih = (const float*)d_in[9];
    const float* gru_whh = (const float*)d_in[10];
    const float* gru_bih = (const float*)d_in[11];
    const float* gru_bhh = (const float*)d_in[12];
    const float* head_w1 = (const float*)d_in[13];
    const float* head_b1 = (const float*)d_in[14];
    const float* head_w2 = (const float*)d_in[15];
    const float* head_b2 = (const float*)d_in[16];
    const int* src = eidx;
    const int* dst = eidx + N_EDGES;

    const size_t NH = (size_t)N_NODES * HD;
    char* p = (char*)d_ws;
    auto alloc = [&](size_t bytes) { char* q = p; p += (bytes + 255) & ~(size_t)255; return q; };
    bf16* S0 = (bf16*)alloc(NH * 2);
    bf16* S1 = (bf16*)alloc(NH * 2);
    bf16* S2 = (bf16*)alloc(NH * 2);
    bf16* w1tH = (bf16*)alloc((size_t)NL * HD * HD * 2);
    bf16* w1tL = (bf16*)alloc((size_t)NL * HD * HD * 2);
    bf16* w2tH = (bf16*)alloc((size_t)NL * HD * HD * 2);
    bf16* w2tL = (bf16*)alloc((size_t)NL * HD * HD * 2);
    bf16* wihtH = (bf16*)alloc((size_t)NL * 3 * HD * HD * 2);
    bf16* wihtL = (bf16*)alloc((size_t)NL * 3 * HD * HD * 2);
    bf16* whhtH = (bf16*)alloc((size_t)NL * 3 * HD * HD * 2);
    bf16* whhtL = (bf16*)alloc((size_t)NL * 3 * HD * HD * 2);
    float* pooled = (float*)alloc((size_t)N_GRAPH * HD * 4);
    float* cnt = (float*)alloc(N_GRAPH * 4);
    int* deg = (int*)alloc((N_NODES + 1) * 4);  // also cursor
    int* offs = (int*)alloc((N_NODES + 1) * 4);
    unsigned short* elist = (unsigned short*)alloc((size_t)N_EDGES * 2);
    // total ~144 MB (proven-safe envelope)

    twcvt_kernel<<<dim3(16, 16, NL), 256, 0, stream>>>(mlp_w1, w1tH, w1tL, HD);
    twcvt_kernel<<<dim3(16, 16, NL), 256, 0, stream>>>(mlp_w2, w2tH, w2tL, HD);
    twcvt_kernel<<<dim3(48, 16, NL), 256, 0, stream>>>(gru_wih, wihtH, wihtL, 3 * HD);
    twcvt_kernel<<<dim3(48, 16, NL), 256, 0, stream>>>(gru_whh, whhtH, whhtL, 3 * HD);

    hipMemsetAsync(deg, 0, (N_NODES + 1) * sizeof(int), stream);
    deg_kernel<<<(N_EDGES + 255) / 256, 256, 0, stream>>>(dst, deg);
    scan_kernel<<<1, 1024, 0, stream>>>(deg, offs);
    hipMemsetAsync(deg, 0, (N_NODES + 1) * sizeof(int), stream);
    bucket_kernel<<<(N_EDGES + 255) / 256, 256, 0, stream>>>(src, dst, offs, deg, elist);

    enc_kernel<<<N_NODES, 256, 0, stream>>>(x, enc_w, enc_b, S0);

    bf16* hcur = S0;
    bf16* hoth = S1;
    // XCD-banded 1-D grids: gemm 8 XCD x 30 row-groups x 4 cols; gru 8 x 59 x 4
    int ggrid = 8 * ((NRG + 7) / 8) * 4;    // 960
    int ugrid = 8 * ((NRG + 3) / 4) * 4;    // 1888

    for (int l = 0; l < NL; l++) {
        size_t wsq = (size_t)l * HD * HD;
        size_t wgq = (size_t)l * 3 * HD * HD;
        const float* b1 = mlp_b1 + (size_t)l * HD;
        const float* b2 = mlp_b2 + (size_t)l * HD;
        const float* bih = gru_bih + (size_t)l * 3 * HD;
        const float* bhh = gru_bhh + (size_t)l * 3 * HD;

        gemm_mfma<true><<<ggrid, 256, 0, stream>>>(hcur, w1tH + wsq, w1tL + wsq, b1, hoth, N_NODES);
        gemm_mfma<false><<<ggrid, 256, 0, stream>>>(hoth, w2tH + wsq, w2tL + wsq, b2, S2, N_NODES);
        gather_kernel<<<N_NODES, 256, 0, stream>>>(S2, hoth, elist, offs);
        gru_mfma<<<ugrid, 256, 0, stream>>>(hoth, hcur, wihtH + wgq, wihtL + wgq,
                                            whhtH + wgq, whhtL + wgq, bih, bhh, S2, N_NODES);
        bf16* newh = S2;
        S2 = hcur;
        hcur = newh;
    }

    pool_kernel<<<dim3(N_GRAPH, 2), 256, 0, stream>>>(hcur, batch, pooled, cnt);
    head_kernel<<<N_GRAPH, 256, 0, stream>>>(pooled, cnt, head_w1, head_b1, head_w2, head_b2,
                                             (float*)d_out);
}